// Round 1
// baseline (715.196 us; speedup 1.0000x reference)
//
#include <hip/hip_runtime.h>
#include <stdint.h>

#define IN_DIM 512
#define OUT_DIM 64

typedef short bf16x8 __attribute__((ext_vector_type(8)));
typedef float f32x4 __attribute__((ext_vector_type(4)));

__device__ inline unsigned short f2bf(float f) {          // RTN-even
    unsigned int u = __float_as_uint(f);
    return (unsigned short)((u + 0x7FFFu + ((u >> 16) & 1u)) >> 16);
}
__device__ inline float bf2f(unsigned short s) {
    return __uint_as_float(((unsigned int)s) << 16);
}

// ---------------- degree histogram (XCD-partitioned dest ranges) ----------------
__global__ void zero_deg_kernel(int* __restrict__ deg, int N) {
    int i = blockIdx.x * blockDim.x + threadIdx.x;
    if (i < N) deg[i] = 0;
}

__global__ __launch_bounds__(256) void hist_part_kernel(const int* __restrict__ col,
                                                        int* __restrict__ deg, int E, int N) {
    int part = blockIdx.x & 7;
    int lo = (int)((long)part * N / 8);
    int hi = (int)((long)(part + 1) * N / 8);
    int stride = (gridDim.x >> 3) * blockDim.x;
    int i = (blockIdx.x >> 3) * blockDim.x + threadIdx.x;
    for (; i < E; i += stride) {
        int c = col[i];
        if (c >= lo && c < hi) atomicAdd(&deg[c], 1);
    }
}

// dinv[i] = 1/sqrt(deg+1), d2[i] = 1/(deg+1)
__global__ void dinv_kernel(const int* __restrict__ deg, float* __restrict__ dinv,
                            float* __restrict__ d2, int N) {
    int i = blockIdx.x * blockDim.x + threadIdx.x;
    if (i < N) {
        float d = (float)deg[i] + 1.0f;
        dinv[i] = 1.0f / sqrtf(d);
        d2[i] = 1.0f / d;
    }
}

// ---------------- pack W into MFMA B-fragment layout, split hi/lo bf16 ----------------
__global__ void pack_w_kernel(const float* __restrict__ W,
                              unsigned short* __restrict__ Bhi,
                              unsigned short* __restrict__ Blo) {
    int tid = blockIdx.x * blockDim.x + threadIdx.x;  // 0..4095
    if (tid >= 4096) return;
    int L = tid & 63;
    int ct = tid >> 6;           // c*16 + t
    int t = ct & 15, c = ct >> 4;
    int o = c * 16 + (L & 15);
    int k0 = t * 32 + (L >> 4) * 8;
    const float* src = W + (size_t)o * IN_DIM + k0;
    #pragma unroll
    for (int j = 0; j < 8; ++j) {
        float w = src[j];
        unsigned short h = f2bf(w);
        Bhi[(size_t)tid * 8 + j] = h;
        Blo[(size_t)tid * 8 + j] = f2bf(w - bf2f(h));
    }
}

// ---------------- parallel exclusive scan: phase 1 (per-block local scan) ----------------
// block = 1024 thr x 4 elems = 4096-entry tile; writes local-exclusive to rowptr, total to bsum
__global__ __launch_bounds__(1024) void scan_local_kernel(const int* __restrict__ deg,
                                                          int* __restrict__ rowptr,
                                                          int* __restrict__ bsum, int N) {
    __shared__ int sm[16];
    int tid = threadIdx.x, lane = tid & 63, wid = tid >> 6;
    int i = blockIdx.x * 4096 + tid * 4;
    int4 v = make_int4(0, 0, 0, 0);
    if (i + 3 < N) {
        v = *(const int4*)(deg + i);
    } else {
        if (i < N) v.x = deg[i];
        if (i + 1 < N) v.y = deg[i + 1];
        if (i + 2 < N) v.z = deg[i + 2];
        if (i + 3 < N) v.w = deg[i + 3];
    }
    int s1 = v.x, s2 = s1 + v.y, s3 = s2 + v.z, s4 = s3 + v.w;
    int incl = s4;
    #pragma unroll
    for (int d = 1; d < 64; d <<= 1) {
        int t = __shfl_up(incl, d, 64);
        if (lane >= d) incl += t;
    }
    if (lane == 63) sm[wid] = incl;
    __syncthreads();
    if (tid == 0) {
        int run = 0;
        #pragma unroll
        for (int w2 = 0; w2 < 16; ++w2) { int t = sm[w2]; sm[w2] = run; run += t; }
        bsum[blockIdx.x] = run;
    }
    __syncthreads();
    int tbase = incl - s4 + sm[wid];
    if (i + 3 < N) {
        *(int4*)(rowptr + i) = make_int4(tbase, tbase + s1, tbase + s2, tbase + s3);
    } else {
        if (i < N)     rowptr[i]     = tbase;
        if (i + 1 < N) rowptr[i + 1] = tbase + s1;
        if (i + 2 < N) rowptr[i + 2] = tbase + s2;
        if (i + 3 < N) rowptr[i + 3] = tbase + s3;
    }
}

// ---------------- scan phase 2: add block offsets, emit cursor copy ----------------
__global__ __launch_bounds__(1024) void scan_add_kernel(int* __restrict__ rowptr,
                                                        int* __restrict__ cursor,
                                                        const int* __restrict__ bsum,
                                                        int N, int nb) {
    __shared__ int soff;
    if (threadIdx.x == 0) {
        int off = 0;
        for (int j = 0; j < (int)blockIdx.x; ++j) off += bsum[j];
        soff = off;
        if ((int)blockIdx.x == nb - 1) {
            int tot = off;
            for (int j = blockIdx.x; j < nb; ++j) tot += bsum[j];
            rowptr[N] = tot;
        }
    }
    __syncthreads();
    int off = soff;
    int i = blockIdx.x * 4096 + threadIdx.x * 4;
    if (i + 3 < N) {
        int4 r = *(int4*)(rowptr + i);
        r.x += off; r.y += off; r.z += off; r.w += off;
        *(int4*)(rowptr + i) = r;
        *(int4*)(cursor + i) = r;
    } else {
        for (int j = 0; j < 4; ++j)
            if (i + j < N) { int r = rowptr[i + j] + off; rowptr[i + j] = r; cursor[i + j] = r; }
    }
}

// ---------------- CSC fill, XCD-partitioned dest ranges ----------------
__global__ __launch_bounds__(256) void fill_part_kernel(const int* __restrict__ row,
                                                        const int* __restrict__ col,
                                                        int* __restrict__ cursor,
                                                        int* __restrict__ csr, int E, int N) {
    int part = blockIdx.x & 7;
    int lo = (int)((long)part * N / 8);
    int hi = (int)((long)(part + 1) * N / 8);
    int stride = (gridDim.x >> 3) * blockDim.x;
    int i = (blockIdx.x >> 3) * blockDim.x + threadIdx.x;
    for (; i < E; i += stride) {
        int c = col[i];
        if (c >= lo && c < hi) {
            int pos = atomicAdd(&cursor[c], 1);
            csr[pos] = row[i];
        }
    }
}

// ---------------- MFMA GEMM: g0 = dinv * (x @ W^T + b) ----------------
__global__ __launch_bounds__(256) void mfma_gemm_kernel(const float* __restrict__ x,
                                                        const unsigned short* __restrict__ Bhi,
                                                        const unsigned short* __restrict__ Blo,
                                                        const float* __restrict__ bias,
                                                        const float* __restrict__ dinv,
                                                        float* __restrict__ h, int N) {
    int lane = threadIdx.x & 63;
    int wid  = __builtin_amdgcn_readfirstlane(threadIdx.x >> 6);
    int quad = lane >> 4, r16 = lane & 15;
    long rowBase = ((long)blockIdx.x * 4 + wid) * 32;
    if (rowBase >= N) return;
    bool full = (rowBase + 32 <= N);

    f32x4 acc[2][4];
    #pragma unroll
    for (int rt = 0; rt < 2; ++rt)
        #pragma unroll
        for (int c = 0; c < 4; ++c) acc[rt][c] = (f32x4){0.f, 0.f, 0.f, 0.f};

    int row0 = (int)rowBase + r16;
    int row1 = (int)rowBase + 16 + r16;
    int row0c = full ? row0 : (row0 < N ? row0 : N - 1);
    int row1c = full ? row1 : (row1 < N ? row1 : N - 1);
    const float* a0p = x + (size_t)row0c * IN_DIM + quad * 8;
    const float* a1p = x + (size_t)row1c * IN_DIM + quad * 8;

    for (int t = 0; t < 16; ++t) {
        bf16x8 bh[4], bl[4];
        #pragma unroll
        for (int c = 0; c < 4; ++c) {
            size_t off = ((size_t)(c * 16 + t) * 64 + lane) * 8;
            union { int4 i; bf16x8 b; } uh, ul;
            uh.i = *(const int4*)(Bhi + off);
            ul.i = *(const int4*)(Blo + off);
            bh[c] = uh.b; bl[c] = ul.b;
        }
        bf16x8 ah[2], al[2];
        #pragma unroll
        for (int rt = 0; rt < 2; ++rt) {
            const float* p = (rt ? a1p : a0p) + t * 32;
            float4 f0 = *(const float4*)p;
            float4 f1 = *(const float4*)(p + 4);
            float v[8] = {f0.x, f0.y, f0.z, f0.w, f1.x, f1.y, f1.z, f1.w};
            #pragma unroll
            for (int j = 0; j < 8; ++j) {
                unsigned short hi = f2bf(v[j]);
                ah[rt][j] = (short)hi;
                al[rt][j] = (short)f2bf(v[j] - bf2f(hi));
            }
        }
        #pragma unroll
        for (int rt = 0; rt < 2; ++rt)
            #pragma unroll
            for (int c = 0; c < 4; ++c) {
                acc[rt][c] = __builtin_amdgcn_mfma_f32_16x16x32_bf16(ah[rt], bh[c], acc[rt][c], 0, 0, 0);
                acc[rt][c] = __builtin_amdgcn_mfma_f32_16x16x32_bf16(ah[rt], bl[c], acc[rt][c], 0, 0, 0);
                acc[rt][c] = __builtin_amdgcn_mfma_f32_16x16x32_bf16(al[rt], bh[c], acc[rt][c], 0, 0, 0);
            }
    }

    float bb[4];
    #pragma unroll
    for (int c = 0; c < 4; ++c) bb[c] = bias[c * 16 + r16];
    #pragma unroll
    for (int rt = 0; rt < 2; ++rt)
        #pragma unroll
        for (int rr = 0; rr < 4; ++rr) {
            int row = (int)rowBase + rt * 16 + quad * 4 + rr;
            if (row < N) {
                float dv = dinv[row];
                #pragma unroll
                for (int c = 0; c < 4; ++c)
                    h[(size_t)row * OUT_DIM + c * 16 + r16] = dv * (acc[rt][c][rr] + bb[c]);
            }
        }
}

// ---------------- one SpMM hop ----------------
// Restructured: 4 lane-groups x 16 lanes; lane loads float4 (16B) so ONE gather
// instruction fetches 4 full 256B rows (1 KB).  Wave owns a contiguous chunk of
// 8 nodes (contiguous csr range); rowptr loaded once per chunk, shuffled out.
// Main loop: 16 edges with 4 csr dword loads + 4 dwordx4 gathers (vs 32 VMEM before).
#define HOP_K 8

__global__ __launch_bounds__(256) void hop_kernel(const float* __restrict__ src,
                                                  float* __restrict__ dst,
                                                  const int* __restrict__ csr,
                                                  const int* __restrict__ rowptr,
                                                  const float* __restrict__ scale, int N) {
    int lane = threadIdx.x & 63;
    int wid  = __builtin_amdgcn_readfirstlane(threadIdx.x >> 6);
    int g    = lane >> 4;       // lane-group 0..3
    int l16  = lane & 15;
    int w  = blockIdx.x * 4 + wid;
    int n0 = w * HOP_K;
    if (n0 >= N) return;
    int nK = (N - n0 < HOP_K) ? (N - n0) : HOP_K;

    int rpv = 0;
    if (lane <= nK) rpv = rowptr[n0 + lane];

    for (int j = 0; j < nK; ++j) {
        int n = n0 + j;
        int s = __shfl(rpv, j, 64);
        int e = __shfl(rpv, j + 1, 64);

        f32x4 self4;
        if (lane < 16) self4 = *(const f32x4*)(src + (size_t)n * OUT_DIM + l16 * 4);

        f32x4 acc = (f32x4){0.f, 0.f, 0.f, 0.f};
        int i = s;
        // main: 16 edges/iter; group g owns edges [i+4g, i+4g+3]
        for (; i + 16 <= e; i += 16) {
            int base = i + 4 * g;
            int i0 = csr[base], i1 = csr[base + 1], i2 = csr[base + 2], i3 = csr[base + 3];
            f32x4 v0 = *(const f32x4*)(src + (size_t)i0 * OUT_DIM + l16 * 4);
            f32x4 v1 = *(const f32x4*)(src + (size_t)i1 * OUT_DIM + l16 * 4);
            f32x4 v2 = *(const f32x4*)(src + (size_t)i2 * OUT_DIM + l16 * 4);
            f32x4 v3 = *(const f32x4*)(src + (size_t)i3 * OUT_DIM + l16 * 4);
            acc += (v0 + v1) + (v2 + v3);
        }
        // mid: 4 edges/iter; group g owns edge i+g
        for (; i + 4 <= e; i += 4) {
            int i0 = csr[i + g];
            acc += *(const f32x4*)(src + (size_t)i0 * OUT_DIM + l16 * 4);
        }
        // tail: remaining (e-i) in [0,4); groups g < e-i take one edge
        if (i + g < e) {
            int i0 = csr[i + g];
            acc += *(const f32x4*)(src + (size_t)i0 * OUT_DIM + l16 * 4);
        }
        // reduce across the 4 lane-groups (xor 16, 32)
        #pragma unroll
        for (int d = 16; d < 64; d <<= 1) {
            acc.x += __shfl_xor(acc.x, d, 64);
            acc.y += __shfl_xor(acc.y, d, 64);
            acc.z += __shfl_xor(acc.z, d, 64);
            acc.w += __shfl_xor(acc.w, d, 64);
        }
        if (lane < 16) {
            float sc = scale[n];
            f32x4 r = (acc + self4) * sc;
            *(f32x4*)(dst + (size_t)n * OUT_DIM + l16 * 4) = r;
        }
    }
}

extern "C" void kernel_launch(void* const* d_in, const int* in_sizes, int n_in,
                              void* d_out, int out_size, void* d_ws, size_t ws_size,
                              hipStream_t stream) {
    const float* x  = (const float*)d_in[0];
    const float* W  = (const float*)d_in[1];
    const float* b  = (const float*)d_in[2];
    const int*   ei = (const int*)d_in[3];
    int N = in_sizes[0] / IN_DIM;   // 100000
    int E = in_sizes[3] / 2;        // 1.6M
    const int* row = ei;
    const int* col = ei + E;
    float* out = (float*)d_out;

    // ---- small scratch in d_ws (~2.2 MB) ----
    float* dinv   = (float*)d_ws;                    // N
    float* d2     = dinv + N;                        // N
    int*   deg    = (int*)(d2 + N);                  // N
    int*   rowptr = deg + N;                         // N+4
    int*   cursor = rowptr + (N + 4);                // N
    int*   bsum   = cursor + N;                      // 32 (scan block sums)
    unsigned short* Bhi = (unsigned short*)(bsum + 32);    // 32768 (64 KB)
    unsigned short* Blo = Bhi + 32768;                     // 32768 (64 KB)

    // ---- big scratch carved from the x input buffer, used only AFTER gemm
    //      has fully consumed x (stream-serialized); harness restores x. ----
    float* xspace = (float*)d_in[0];
    float* hbuf   = xspace;                                   // N*64 floats (25.6 MB)
    int*   csr    = (int*)(xspace + (size_t)N * OUT_DIM);     // E ints (6.4 MB)

    dim3 blk(256);
    int gN = (N + 255) / 256;
    int gPart = 8 * 784;              // 8 XCD-parts x 784 blocks
    int nbScan = (N + 4095) / 4096;   // 25

    // 1) degrees + dinv/d2 (reads edge_index only)
    zero_deg_kernel<<<gN, blk, 0, stream>>>(deg, N);
    hist_part_kernel<<<gPart, blk, 0, stream>>>(col, deg, E, N);
    dinv_kernel<<<gN, blk, 0, stream>>>(deg, dinv, d2, N);

    // 2) pack W into split-bf16 MFMA B-fragments
    pack_w_kernel<<<16, blk, 0, stream>>>(W, Bhi, Blo);

    // 3) MFMA GEMM consumes x completely; epilogue pre-scales by dinv -> g0 in d_out
    mfma_gemm_kernel<<<(N + 127) / 128, blk, 0, stream>>>(x, Bhi, Blo, b, dinv, out, N);

    // 4) CSC build (after gemm in stream order; csr lives in x-space)
    scan_local_kernel<<<nbScan, 1024, 0, stream>>>(deg, rowptr, bsum, N);
    scan_add_kernel<<<nbScan, 1024, 0, stream>>>(rowptr, cursor, bsum, N, nbScan);
    fill_part_kernel<<<gPart, blk, 0, stream>>>(row, col, cursor, csr, E, N);

    // 5) 4 hops in g-form; last hop applies dinv (not dinv^2) -> h4 in d_out
    int chunks = (N + HOP_K - 1) / HOP_K;
    int gH = (chunks + 3) / 4;
    hop_kernel<<<gH, blk, 0, stream>>>(out, hbuf, csr, rowptr, d2, N);    // g1
    hop_kernel<<<gH, blk, 0, stream>>>(hbuf, out, csr, rowptr, d2, N);    // g2
    hop_kernel<<<gH, blk, 0, stream>>>(out, hbuf, csr, rowptr, d2, N);    // g3
    hop_kernel<<<gH, blk, 0, stream>>>(hbuf, out, csr, rowptr, dinv, N);  // h4
}